// Round 3
// baseline (12219.650 us; speedup 1.0000x reference)
//
#include <hip/hip_runtime.h>

typedef float f32x4 __attribute__((ext_vector_type(4)));
typedef short short8v __attribute__((ext_vector_type(8)));

constexpr int TSTEPS = 512;

__device__ __forceinline__ float silu_f(float x) {
    return x / (1.0f + __expf(-x));
}

// 3-term bf16 split by truncation: x = hi + mid + lo (+ residual ~2^-24 |x|)
__device__ __forceinline__ void split3(float x, short &s0, short &s1, short &s2) {
    unsigned u1 = __float_as_uint(x) & 0xFFFF0000u;
    float r1 = x - __uint_as_float(u1);
    unsigned u2 = __float_as_uint(r1) & 0xFFFF0000u;
    float r2 = r1 - __uint_as_float(u2);
    s0 = (short)(u1 >> 16);
    s1 = (short)(u2 >> 16);
    s2 = (short)(__float_as_uint(r2) >> 16);
}

// 6-product triple-split MFMA: keeps all terms >= ~2^-24 relative
__device__ __forceinline__ f32x4 mfma6(const short8v *A, const short8v *B, f32x4 c) {
    c = __builtin_amdgcn_mfma_f32_16x16x32_bf16(A[0], B[0], c, 0, 0, 0);
    c = __builtin_amdgcn_mfma_f32_16x16x32_bf16(A[0], B[1], c, 0, 0, 0);
    c = __builtin_amdgcn_mfma_f32_16x16x32_bf16(A[1], B[0], c, 0, 0, 0);
    c = __builtin_amdgcn_mfma_f32_16x16x32_bf16(A[0], B[2], c, 0, 0, 0);
    c = __builtin_amdgcn_mfma_f32_16x16x32_bf16(A[1], B[1], c, 0, 0, 0);
    c = __builtin_amdgcn_mfma_f32_16x16x32_bf16(A[2], B[0], c, 0, 0, 0);
    return c;
}

// XOR chunk swizzle on a float index within rows of 128 floats (512B, chunk-aligned):
// flips 16B-chunk bits 0..2 by the row (batch) id -> uniform 8 lanes per bank-slot.
__device__ __forceinline__ int swz(int idx, int b) { return idx ^ ((b & 7) << 2); }

// Block: 256 threads = 4 waves, 16 batch rows.
// A-operand = W^T (weights, persistent in VGPR/AGPR), B = activations,
// C: col(lane&15)=batch, row=(lane>>4)*4+reg = output feature j.
// layer1: M-split (wave w owns j in [32w,32w+32), K=8 zero-padded).
// layer2: K-split (wave w owns k in [32w,32w+32)), partials reduced via LDS.
// layer3: pure fp32 VALU dot + shfl_xor butterfly (+ LDS reduce across waves).
__global__ __launch_bounds__(256, 2)
void odernn_v3(const float* __restrict__ quat,
               const float* __restrict__ W1, const float* __restrict__ b1,
               const float* __restrict__ W2, const float* __restrict__ b2,
               const float* __restrict__ W3, const float* __restrict__ b3,
               float* __restrict__ out)
{
    __shared__ float sx1[16 * 128];      // [b][k] fp32, swizzled
    __shared__ float sx2p[4 * 16 * 128]; // [wave][b][j] fp32 partials, swizzled
    __shared__ float sk3[4][16][4];      // layer3 partials per wave
    __shared__ float sb1[128];
    __shared__ float sb2[128];

    const int tid  = threadIdx.x;
    const int w    = tid >> 6;
    const int lane = tid & 63;
    const int l15  = lane & 15;   // batch col
    const int g    = lane >> 4;   // k-subgroup
    const int rowbase = blockIdx.x * 16;

    if (tid < 128) { sb1[tid] = b1[tid]; sb2[tid] = b2[tid]; }

    // ---- persistent weight fragments ----
    short8v A2[8][3];   // W2^T: j = 16*mt + l15, k = 32w + 8g + e
    #pragma unroll
    for (int mt = 0; mt < 8; ++mt) {
        #pragma unroll
        for (int e = 0; e < 8; ++e) {
            float x = W2[(32*w + 8*g + e) * 128 + (16*mt + l15)];
            short t0, t1, t2; split3(x, t0, t1, t2);
            A2[mt][0][e] = t0; A2[mt][1][e] = t1; A2[mt][2][e] = t2;
        }
    }
    short8v A1[2][3];   // W1^T: j = 32w + 16mt + l15, k = 8g+e (real only g==0)
    #pragma unroll
    for (int mt = 0; mt < 2; ++mt) {
        #pragma unroll
        for (int e = 0; e < 8; ++e) {
            int k = 8*g + e;
            float x = (k < 8) ? W1[k * 128 + (32*w + 16*mt + l15)] : 0.0f;
            short t0, t1, t2; split3(x, t0, t1, t2);
            A1[mt][0][e] = t0; A1[mt][1][e] = t1; A1[mt][2][e] = t2;
        }
    }
    f32x4 W3v[8];       // W3 rows for k = 32w + 8g + e (fp32, for VALU layer3)
    #pragma unroll
    for (int e = 0; e < 8; ++e)
        W3v[e] = *(const f32x4*)&W3[(32*w + 8*g + e) * 4];
    f32x4 b3v = *(const f32x4*)b3;

    __syncthreads();

    f32x4 h  = {1.0f, 0.0f, 0.0f, 0.0f};
    f32x4 k1 = {0,0,0,0}, k2 = {0,0,0,0}, k3v = {0,0,0,0};
    const float* qp = quat + (size_t)(rowbase + l15) * TSTEPS * 4;

    #pragma unroll 1
    for (int t = 0; t < TSTEPS; ++t) {
        f32x4 q = *(const f32x4*)(qp + 4 * t);
        f32x4 hnew = {0,0,0,0};

        #pragma unroll 1
        for (int s = 0; s < 4; ++s) {
            f32x4 hs = h;
            if (s == 1)      hs += k1 * (1.0f/3.0f);
            else if (s == 2) hs += k2 - k1 * (1.0f/3.0f);
            else if (s == 3) hs += k1 - k2 + k3v;

            // ---- layer 1 (MFMA, M-split) ----
            short8v B0[3];
            {
                float xv[8] = {hs.x, hs.y, hs.z, hs.w, q.x, q.y, q.z, q.w};
                #pragma unroll
                for (int e = 0; e < 8; ++e) {
                    float x = (g == 0) ? xv[e] : 0.0f;
                    short t0, t1, t2; split3(x, t0, t1, t2);
                    B0[0][e] = t0; B0[1][e] = t1; B0[2][e] = t2;
                }
            }
            f32x4 c1[2];
            c1[0] = *(const f32x4*)&sb1[32*w + 4*g];
            c1[1] = *(const f32x4*)&sb1[32*w + 16 + 4*g];
            c1[0] = mfma6(A1[0], B0, c1[0]);
            c1[1] = mfma6(A1[1], B0, c1[1]);

            #pragma unroll
            for (int mt = 0; mt < 2; ++mt) {
                f32x4 v;
                v.x = silu_f(c1[mt].x); v.y = silu_f(c1[mt].y);
                v.z = silu_f(c1[mt].z); v.w = silu_f(c1[mt].w);
                *(f32x4*)&sx1[swz(l15*128 + 32*w + 16*mt + 4*g, l15)] = v;
            }

            // ---- layer 2 (MFMA, K-split): read own k-slice (same wave wrote it) ----
            f32x4 r0 = *(const f32x4*)&sx1[swz(l15*128 + 32*w + 8*g,     l15)];
            f32x4 r1 = *(const f32x4*)&sx1[swz(l15*128 + 32*w + 8*g + 4, l15)];
            short8v B2[3];
            {
                float xr[8] = {r0.x, r0.y, r0.z, r0.w, r1.x, r1.y, r1.z, r1.w};
                #pragma unroll
                for (int e = 0; e < 8; ++e) {
                    short t0, t1, t2; split3(xr[e], t0, t1, t2);
                    B2[0][e] = t0; B2[1][e] = t1; B2[2][e] = t2;
                }
            }
            f32x4 c2[8];
            #pragma unroll
            for (int mt = 0; mt < 8; ++mt) {
                f32x4 z = {0,0,0,0};
                c2[mt] = mfma6(A2[mt], B2, z);
            }
            #pragma unroll
            for (int mt = 0; mt < 8; ++mt)
                *(f32x4*)&sx2p[swz((w*16 + l15)*128 + 16*mt + 4*g, l15)] = c2[mt];
            __syncthreads();

            // ---- reduce partials on own k-slice + bias + silu ----
            f32x4 xa = {0,0,0,0}, xb = {0,0,0,0};
            #pragma unroll
            for (int w2 = 0; w2 < 4; ++w2) {
                xa += *(const f32x4*)&sx2p[swz((w2*16 + l15)*128 + 32*w + 8*g,     l15)];
                xb += *(const f32x4*)&sx2p[swz((w2*16 + l15)*128 + 32*w + 8*g + 4, l15)];
            }
            xa += *(const f32x4*)&sb2[32*w + 8*g];
            xb += *(const f32x4*)&sb2[32*w + 8*g + 4];

            // ---- layer 3 (fp32 VALU dot over own 8 k's) ----
            float v[8] = {silu_f(xa.x), silu_f(xa.y), silu_f(xa.z), silu_f(xa.w),
                          silu_f(xb.x), silu_f(xb.y), silu_f(xb.z), silu_f(xb.w)};
            f32x4 p = {0,0,0,0};
            #pragma unroll
            for (int e = 0; e < 8; ++e) p += v[e] * W3v[e];
            // butterfly over the 4 k-subgroups (lane bits 4,5)
            #pragma unroll
            for (int mx = 16; mx < 64; mx <<= 1) {
                p.x += __shfl_xor(p.x, mx, 64);
                p.y += __shfl_xor(p.y, mx, 64);
                p.z += __shfl_xor(p.z, mx, 64);
                p.w += __shfl_xor(p.w, mx, 64);
            }
            if (g == 0) *(f32x4*)&sk3[w][l15][0] = p;
            __syncthreads();

            f32x4 ks = b3v;
            #pragma unroll
            for (int w2 = 0; w2 < 4; ++w2)
                ks += *(const f32x4*)&sk3[w2][l15][0];

            const float wgt = (s == 1 || s == 2) ? 0.375f : 0.125f;
            hnew += ks * wgt;
            if (s == 0)      k1  = ks;
            else if (s == 1) k2  = ks;
            else if (s == 2) k3v = ks;
        }
        h += hnew;
    }

    if (tid < 16)
        *(f32x4*)&out[(size_t)(rowbase + l15) * 4] = h;
}

extern "C" void kernel_launch(void* const* d_in, const int* in_sizes, int n_in,
                              void* d_out, int out_size, void* d_ws, size_t ws_size,
                              hipStream_t stream)
{
    const float* quat = (const float*)d_in[0];
    const float* W1   = (const float*)d_in[1];
    const float* b1   = (const float*)d_in[2];
    const float* W2   = (const float*)d_in[3];
    const float* b2   = (const float*)d_in[4];
    const float* W3   = (const float*)d_in[5];
    const float* b3   = (const float*)d_in[6];
    float* out        = (float*)d_out;

    const int B = in_sizes[0] / (TSTEPS * 4);   // 16384
    dim3 grid(B / 16), block(256);
    hipLaunchKernelGGL(odernn_v3, grid, block, 0, stream,
                       quat, W1, b1, W2, b2, W3, b3, out);
}

// Round 4
// 9206.008 us; speedup vs baseline: 1.3274x; 1.3274x over previous
//
#include <hip/hip_runtime.h>

typedef float f32x4 __attribute__((ext_vector_type(4)));
typedef short short8v __attribute__((ext_vector_type(8)));
typedef unsigned int uint;

constexpr int TSTEPS = 512;

union FragU { uint u[4]; short8v v; };

__device__ __forceinline__ float silu_f(float x) {
    // x * sigmoid(x); fast division (rcp-based) is fine at bf16-split precision
    return __fdividef(x, 1.0f + __expf(-x));
}

// 3-term bf16 truncation split; results carry the bf16 pattern in the TOP 16 bits.
__device__ __forceinline__ void split3u(float x, uint &h, uint &m, uint &l) {
    uint ux = __float_as_uint(x);
    h = ux & 0xFFFF0000u;
    float r1 = x - __uint_as_float(h);
    uint ur1 = __float_as_uint(r1);
    m = ur1 & 0xFFFF0000u;
    float r2 = r1 - __uint_as_float(m);
    l = __float_as_uint(r2) & 0xFFFF0000u;
}

// pack two "bf16-in-top-half" uints into one uint: a -> low short, b -> high short
__device__ __forceinline__ uint pack_hi(uint a, uint b) {
    return (a >> 16) | (b & 0xFFFF0000u);
}

// 6-product triple-split MFMA (W 3-level x X 3-level, all terms >= ~2^-26 kept)
__device__ __forceinline__ f32x4 mfma6(const short8v *A, short8v Bh, short8v Bm,
                                       short8v Bl, f32x4 c) {
    c = __builtin_amdgcn_mfma_f32_16x16x32_bf16(A[0], Bh, c, 0, 0, 0);
    c = __builtin_amdgcn_mfma_f32_16x16x32_bf16(A[0], Bm, c, 0, 0, 0);
    c = __builtin_amdgcn_mfma_f32_16x16x32_bf16(A[1], Bh, c, 0, 0, 0);
    c = __builtin_amdgcn_mfma_f32_16x16x32_bf16(A[0], Bl, c, 0, 0, 0);
    c = __builtin_amdgcn_mfma_f32_16x16x32_bf16(A[1], Bm, c, 0, 0, 0);
    c = __builtin_amdgcn_mfma_f32_16x16x32_bf16(A[2], Bh, c, 0, 0, 0);
    return c;
}

// 4 waves / 256 threads / 16 batch rows per block.
// layer1: M-split (wave w owns j in [32w,32w+32)), K=8 packed into K=32 slots
//         (2 MFMAs carry all 6 split products).
// layer2: M-split, full K=128 per wave; x1 crosses waves PRE-SPLIT as bf16
//         triplets in LDS (producer-side split3, consumer reads b128 only).
// layer3: fp32 VALU dot with W3 broadcast-read from LDS + shfl butterfly +
//         tiny LDS reduce across waves.
__global__ __launch_bounds__(256, 2)
void odernn_v4(const float* __restrict__ quat,
               const float* __restrict__ W1, const float* __restrict__ b1,
               const float* __restrict__ W2, const float* __restrict__ b2,
               const float* __restrict__ W3, const float* __restrict__ b3,
               float* __restrict__ out)
{
    // x1 pre-split: [lev][kchunk(16)][batch(16)][8 shorts] ; 16B granule = l15 slot
    __shared__ short sx1[3 * 16 * 16 * 8];      // 12 KB
    __shared__ float sb1[128];
    __shared__ float sb2[128];
    __shared__ float sW3[128 * 4];              // 2 KB, broadcast reads
    __shared__ float sk3[4][16][4];             // layer3 per-wave partials

    const int tid  = threadIdx.x;
    const int w    = tid >> 6;
    const int lane = tid & 63;
    const int l15  = lane & 15;   // batch col (B/C) or M-row (A)
    const int g    = lane >> 4;   // k-subgroup
    const int rowbase = blockIdx.x * 16;

    if (tid < 128) { sb1[tid] = b1[tid]; sb2[tid] = b2[tid]; }
    for (int i = tid; i < 512; i += 256) sW3[i] = W3[i];

    // ---- persistent weight fragments ----
    // W2^T fragments: j = 32w + 16mt + l15, k = 32kt + 8g + e
    short8v A2[2][4][3];
    #pragma unroll
    for (int mt = 0; mt < 2; ++mt) {
        #pragma unroll
        for (int kt = 0; kt < 4; ++kt) {
            #pragma unroll
            for (int e = 0; e < 8; ++e) {
                float x = W2[(32*kt + 8*g + e) * 128 + (32*w + 16*mt + l15)];
                uint uh, um, ul; split3u(x, uh, um, ul);
                A2[mt][kt][0][e] = (short)(uh >> 16);
                A2[mt][kt][1][e] = (short)(um >> 16);
                A2[mt][kt][2][e] = (short)(ul >> 16);
            }
        }
    }
    // W1^T packed fragments: j = 32w + 16mt + l15, input index e (0..7)
    // A1a groups: [Whi | Whi | Wmid | Whi] ; A1b: [Wlo | Wmid | 0 | 0]
    short8v A1a[2], A1b[2];
    #pragma unroll
    for (int mt = 0; mt < 2; ++mt) {
        #pragma unroll
        for (int e = 0; e < 8; ++e) {
            float x = W1[e * 128 + (32*w + 16*mt + l15)];
            uint uh, um, ul; split3u(x, uh, um, ul);
            uint ua = (g == 2) ? um : uh;
            uint ub = (g == 0) ? ul : ((g == 1) ? um : 0u);
            A1a[mt][e] = (short)(ua >> 16);
            A1b[mt][e] = (short)(ub >> 16);
        }
    }
    f32x4 b3v = *(const f32x4*)b3;

    __syncthreads();

    f32x4 h  = {1.0f, 0.0f, 0.0f, 0.0f};
    f32x4 k1 = {0,0,0,0}, k2 = {0,0,0,0}, k3v = {0,0,0,0};
    const float* qp = quat + (size_t)(rowbase + l15) * TSTEPS * 4;

    const bool gm = (g == 1), gl = (g == 3);

    #pragma unroll 1
    for (int t = 0; t < TSTEPS; ++t) {
        f32x4 q = *(const f32x4*)(qp + 4 * t);
        // per-t: split q, select level by group, pack (B0 elements 4..7)
        uint q01, q23;
        {
            uint s0[4], s1[4], s2[4], sel[4];
            split3u(q.x, s0[0], s1[0], s2[0]);
            split3u(q.y, s0[1], s1[1], s2[1]);
            split3u(q.z, s0[2], s1[2], s2[2]);
            split3u(q.w, s0[3], s1[3], s2[3]);
            #pragma unroll
            for (int r = 0; r < 4; ++r) sel[r] = gm ? s1[r] : (gl ? s2[r] : s0[r]);
            q01 = pack_hi(sel[0], sel[1]);
            q23 = pack_hi(sel[2], sel[3]);
        }

        f32x4 hnew = {0,0,0,0};

        #pragma unroll
        for (int s = 0; s < 4; ++s) {
            f32x4 hs = h;
            if (s == 1)      hs += k1 * (1.0f/3.0f);
            else if (s == 2) hs += k2 - k1 * (1.0f/3.0f);
            else if (s == 3) hs += k1 - k2 + k3v;

            // ---- B0: split hs, per-group level select, pack with q half ----
            FragU b0;
            {
                uint s0[4], s1[4], s2[4], sel[4];
                split3u(hs.x, s0[0], s1[0], s2[0]);
                split3u(hs.y, s0[1], s1[1], s2[1]);
                split3u(hs.z, s0[2], s1[2], s2[2]);
                split3u(hs.w, s0[3], s1[3], s2[3]);
                #pragma unroll
                for (int r = 0; r < 4; ++r) sel[r] = gm ? s1[r] : (gl ? s2[r] : s0[r]);
                b0.u[0] = pack_hi(sel[0], sel[1]);
                b0.u[1] = pack_hi(sel[2], sel[3]);
                b0.u[2] = q01;
                b0.u[3] = q23;
            }

            // ---- layer 1: 2 packed MFMAs per mt ----
            f32x4 c1[2];
            #pragma unroll
            for (int mt = 0; mt < 2; ++mt) {
                c1[mt] = *(const f32x4*)&sb1[32*w + 16*mt + 4*g];
                c1[mt] = __builtin_amdgcn_mfma_f32_16x16x32_bf16(A1a[mt], b0.v, c1[mt], 0, 0, 0);
                c1[mt] = __builtin_amdgcn_mfma_f32_16x16x32_bf16(A1b[mt], b0.v, c1[mt], 0, 0, 0);
            }

            // ---- silu + producer-side split3 -> LDS (bf16 triplets) ----
            #pragma unroll
            for (int mt = 0; mt < 2; ++mt) {
                uint uh[4], um[4], ul[4];
                #pragma unroll
                for (int r = 0; r < 4; ++r) {
                    float v = silu_f(c1[mt][r]);
                    split3u(v, uh[r], um[r], ul[r]);
                }
                const int kc = 4*w + 2*mt + (g >> 1);
                const int half = (g & 1) * 4;
                uint2 p0 = {pack_hi(uh[0], uh[1]), pack_hi(uh[2], uh[3])};
                uint2 p1 = {pack_hi(um[0], um[1]), pack_hi(um[2], um[3])};
                uint2 p2 = {pack_hi(ul[0], ul[1]), pack_hi(ul[2], ul[3])};
                *(uint2*)&sx1[((0*16 + kc)*16 + l15)*8 + half] = p0;
                *(uint2*)&sx1[((1*16 + kc)*16 + l15)*8 + half] = p1;
                *(uint2*)&sx1[((2*16 + kc)*16 + l15)*8 + half] = p2;
            }
            __syncthreads();

            // ---- layer 2: full-K per wave, pre-split B from LDS ----
            f32x4 c2[2];
            c2[0] = *(const f32x4*)&sb2[32*w + 4*g];
            c2[1] = *(const f32x4*)&sb2[32*w + 16 + 4*g];
            #pragma unroll
            for (int kt = 0; kt < 4; ++kt) {
                short8v Bh = *(const short8v*)&sx1[((0*16 + kt*4 + g)*16 + l15)*8];
                short8v Bm = *(const short8v*)&sx1[((1*16 + kt*4 + g)*16 + l15)*8];
                short8v Bl = *(const short8v*)&sx1[((2*16 + kt*4 + g)*16 + l15)*8];
                c2[0] = mfma6(A2[0][kt], Bh, Bm, Bl, c2[0]);
                c2[1] = mfma6(A2[1][kt], Bh, Bm, Bl, c2[1]);
            }

            // ---- layer 3: fp32 dot with broadcast W3 rows ----
            f32x4 p = {0,0,0,0};
            #pragma unroll
            for (int mt = 0; mt < 2; ++mt) {
                #pragma unroll
                for (int r = 0; r < 4; ++r) {
                    const int j = 32*w + 16*mt + 4*g + r;
                    float xv = silu_f(c2[mt][r]);
                    p += xv * (*(const f32x4*)&sW3[j * 4]);
                }
            }
            #pragma unroll
            for (int mx = 16; mx < 64; mx <<= 1) {
                p.x += __shfl_xor(p.x, mx, 64);
                p.y += __shfl_xor(p.y, mx, 64);
                p.z += __shfl_xor(p.z, mx, 64);
                p.w += __shfl_xor(p.w, mx, 64);
            }
            if (g == 0) *(f32x4*)&sk3[w][l15][0] = p;
            __syncthreads();

            f32x4 ks = b3v;
            #pragma unroll
            for (int w2 = 0; w2 < 4; ++w2)
                ks += *(const f32x4*)&sk3[w2][l15][0];

            const float wgt = (s == 1 || s == 2) ? 0.375f : 0.125f;
            hnew += ks * wgt;
            if (s == 0)      k1  = ks;
            else if (s == 1) k2  = ks;
            else if (s == 2) k3v = ks;
        }
        h += hnew;
    }

    if (tid < 16)
        *(f32x4*)&out[(size_t)(rowbase + l15) * 4] = h;
}

extern "C" void kernel_launch(void* const* d_in, const int* in_sizes, int n_in,
                              void* d_out, int out_size, void* d_ws, size_t ws_size,
                              hipStream_t stream)
{
    const float* quat = (const float*)d_in[0];
    const float* W1   = (const float*)d_in[1];
    const float* b1   = (const float*)d_in[2];
    const float* W2   = (const float*)d_in[3];
    const float* b2   = (const float*)d_in[4];
    const float* W3   = (const float*)d_in[5];
    const float* b3   = (const float*)d_in[6];
    float* out        = (float*)d_out;

    const int B = in_sizes[0] / (TSTEPS * 4);   // 16384
    dim3 grid(B / 16), block(256);
    hipLaunchKernelGGL(odernn_v4, grid, block, 0, stream,
                       quat, W1, b1, W2, b2, W3, b3, out);
}

// Round 5
// 8985.889 us; speedup vs baseline: 1.3599x; 1.0245x over previous
//
#include <hip/hip_runtime.h>

typedef float f32x4 __attribute__((ext_vector_type(4)));
typedef short short8v __attribute__((ext_vector_type(8)));
typedef unsigned int uint;

constexpr int TSTEPS = 512;

union FragU { uint u[4]; short8v v; };

__device__ __forceinline__ float silu_f(float x) {
    return __fdividef(x, 1.0f + __expf(-x));
}

// 3-term bf16 truncation split; bf16 patterns in TOP 16 bits of each uint
__device__ __forceinline__ void split3u(float x, uint &h, uint &m, uint &l) {
    uint ux = __float_as_uint(x);
    h = ux & 0xFFFF0000u;
    float r1 = x - __uint_as_float(h);
    uint ur1 = __float_as_uint(r1);
    m = ur1 & 0xFFFF0000u;
    float r2 = r1 - __uint_as_float(m);
    l = __float_as_uint(r2) & 0xFFFF0000u;
}

// (a>>16)|(b&0xFFFF0000) in one v_perm_b32
__device__ __forceinline__ uint pack_hi(uint a, uint b) {
    return __builtin_amdgcn_perm(b, a, 0x07060302u);
}

// 6-product triple-split MFMA (all kept terms >= ~2^-26 relative)
__device__ __forceinline__ f32x4 mfma6(const short8v *A, short8v Bh, short8v Bm,
                                       short8v Bl, f32x4 c) {
    c = __builtin_amdgcn_mfma_f32_16x16x32_bf16(A[0], Bh, c, 0, 0, 0);
    c = __builtin_amdgcn_mfma_f32_16x16x32_bf16(A[0], Bm, c, 0, 0, 0);
    c = __builtin_amdgcn_mfma_f32_16x16x32_bf16(A[1], Bh, c, 0, 0, 0);
    c = __builtin_amdgcn_mfma_f32_16x16x32_bf16(A[0], Bl, c, 0, 0, 0);
    c = __builtin_amdgcn_mfma_f32_16x16x32_bf16(A[1], Bm, c, 0, 0, 0);
    c = __builtin_amdgcn_mfma_f32_16x16x32_bf16(A[2], Bh, c, 0, 0, 0);
    return c;
}

// split 4 floats, select level by k-subgroup, pack to 2 uints (4 bf16)
__device__ __forceinline__ void level_pack(const f32x4 v, const bool gm, const bool gl,
                                           uint &o01, uint &o23) {
    uint s0[4], s1[4], s2[4], sel[4];
    split3u(v.x, s0[0], s1[0], s2[0]);
    split3u(v.y, s0[1], s1[1], s2[1]);
    split3u(v.z, s0[2], s1[2], s2[2]);
    split3u(v.w, s0[3], s1[3], s2[3]);
#pragma unroll
    for (int r = 0; r < 4; ++r) sel[r] = gm ? s1[r] : (gl ? s2[r] : s0[r]);
    o01 = pack_hi(sel[0], sel[1]);
    o23 = pack_hi(sel[2], sel[3]);
}

// silu + producer-side split -> bf16 triplets in LDS
__device__ __forceinline__ void producer_store(const f32x4 c1, short* sx1g,
                                               int kc, int half, int l15) {
    uint uh[4], um[4], ul[4];
#pragma unroll
    for (int r = 0; r < 4; ++r) {
        float v = silu_f(c1[r]);
        split3u(v, uh[r], um[r], ul[r]);
    }
    uint2 p0 = {pack_hi(uh[0], uh[1]), pack_hi(uh[2], uh[3])};
    uint2 p1 = {pack_hi(um[0], um[1]), pack_hi(um[2], um[3])};
    uint2 p2 = {pack_hi(ul[0], ul[1]), pack_hi(ul[2], ul[3])};
    *(uint2*)&sx1g[((0 * 16 + kc) * 16 + l15) * 8 + half] = p0;
    *(uint2*)&sx1g[((1 * 16 + kc) * 16 + l15) * 8 + half] = p1;
    *(uint2*)&sx1g[((2 * 16 + kc) * 16 + l15) * 8 + half] = p2;
}

// layer1 (packed K: 2 MFMAs carry all 6 split products) + producer store
__device__ __forceinline__ void phase1(const f32x4 hs, uint q01, uint q23,
                                       bool gm, bool gl, int w, int g, int l15,
                                       const short8v* A1a, const short8v* A1b,
                                       const float* sb1, short* sx1g) {
    FragU b0;
    level_pack(hs, gm, gl, b0.u[0], b0.u[1]);
    b0.u[2] = q01; b0.u[3] = q23;
    f32x4 c1_0 = *(const f32x4*)&sb1[32 * w + 4 * g];
    f32x4 c1_1 = *(const f32x4*)&sb1[32 * w + 16 + 4 * g];
    c1_0 = __builtin_amdgcn_mfma_f32_16x16x32_bf16(A1a[0], b0.v, c1_0, 0, 0, 0);
    c1_0 = __builtin_amdgcn_mfma_f32_16x16x32_bf16(A1b[0], b0.v, c1_0, 0, 0, 0);
    c1_1 = __builtin_amdgcn_mfma_f32_16x16x32_bf16(A1a[1], b0.v, c1_1, 0, 0, 0);
    c1_1 = __builtin_amdgcn_mfma_f32_16x16x32_bf16(A1b[1], b0.v, c1_1, 0, 0, 0);
    const int half = (g & 1) * 4;
    producer_store(c1_0, sx1g, 4 * w + (g >> 1),     half, l15);
    producer_store(c1_1, sx1g, 4 * w + 2 + (g >> 1), half, l15);
}

// layer2: full-K M-split, pre-split B from LDS
__device__ __forceinline__ void layer2(const short8v (&A2)[2][4][3], const float* sb2,
                                       const short* sx1g, int w, int g, int l15,
                                       f32x4 &c0, f32x4 &c1) {
    c0 = *(const f32x4*)&sb2[32 * w + 4 * g];
    c1 = *(const f32x4*)&sb2[32 * w + 16 + 4 * g];
#pragma unroll
    for (int kt = 0; kt < 4; ++kt) {
        short8v Bh = *(const short8v*)&sx1g[((0 * 16 + kt * 4 + g) * 16 + l15) * 8];
        short8v Bm = *(const short8v*)&sx1g[((1 * 16 + kt * 4 + g) * 16 + l15) * 8];
        short8v Bl = *(const short8v*)&sx1g[((2 * 16 + kt * 4 + g) * 16 + l15) * 8];
        c0 = mfma6(A2[0][kt], Bh, Bm, Bl, c0);
        c1 = mfma6(A2[1][kt], Bh, Bm, Bl, c1);
    }
}

__device__ __forceinline__ f32x4 bfly(f32x4 p) {
#pragma unroll
    for (int mx = 16; mx < 64; mx <<= 1) {
        p.x += __shfl_xor(p.x, mx, 64);
        p.y += __shfl_xor(p.y, mx, 64);
        p.z += __shfl_xor(p.z, mx, 64);
        p.w += __shfl_xor(p.w, mx, 64);
    }
    return p;
}

// 256 threads / 4 waves; TWO independent 16-row groups (A,B) per block for ILP.
// Weights shared between groups; only activation state duplicated.
__global__ __launch_bounds__(256, 2)
void odernn_v5(const float* __restrict__ quat,
               const float* __restrict__ W1, const float* __restrict__ b1,
               const float* __restrict__ W2, const float* __restrict__ b2,
               const float* __restrict__ W3, const float* __restrict__ b3,
               float* __restrict__ out)
{
    __shared__ short sx1buf[2][3 * 16 * 16 * 8];   // 24 KB
    __shared__ float sb1[128];
    __shared__ float sb2[128];
    __shared__ float sW3[128 * 4];
    __shared__ float sk3[2][4][16][4];

    const int tid  = threadIdx.x;
    const int w    = tid >> 6;
    const int lane = tid & 63;
    const int l15  = lane & 15;
    const int g    = lane >> 4;
    const int rowbase = blockIdx.x * 32;

    short* const sx1A = &sx1buf[0][0];
    short* const sx1B = &sx1buf[1][0];

    if (tid < 128) { sb1[tid] = b1[tid]; sb2[tid] = b2[tid]; }
    for (int i = tid; i < 512; i += 256) sW3[i] = W3[i];

    // ---- persistent weight fragments (shared by both groups) ----
    short8v A2[2][4][3];   // W2^T: j = 32w + 16mt + l15, k = 32kt + 8g + e
#pragma unroll
    for (int mt = 0; mt < 2; ++mt) {
#pragma unroll
        for (int kt = 0; kt < 4; ++kt) {
#pragma unroll
            for (int e = 0; e < 8; ++e) {
                float x = W2[(32 * kt + 8 * g + e) * 128 + (32 * w + 16 * mt + l15)];
                uint uh, um, ul; split3u(x, uh, um, ul);
                A2[mt][kt][0][e] = (short)(uh >> 16);
                A2[mt][kt][1][e] = (short)(um >> 16);
                A2[mt][kt][2][e] = (short)(ul >> 16);
            }
        }
    }
    // W1^T packed: A1a groups [Whi|Whi|Wmid|Whi], A1b [Wlo|Wmid|0|0]
    short8v A1a[2], A1b[2];
#pragma unroll
    for (int mt = 0; mt < 2; ++mt) {
#pragma unroll
        for (int e = 0; e < 8; ++e) {
            float x = W1[e * 128 + (32 * w + 16 * mt + l15)];
            uint uh, um, ul; split3u(x, uh, um, ul);
            uint ua = (g == 2) ? um : uh;
            uint ub = (g == 0) ? ul : ((g == 1) ? um : 0u);
            A1a[mt][e] = (short)(ua >> 16);
            A1b[mt][e] = (short)(ub >> 16);
        }
    }
    f32x4 b3v = *(const f32x4*)b3;

    __syncthreads();

    f32x4 hA = {1.0f, 0, 0, 0}, k1A = {0,0,0,0}, k2A = {0,0,0,0}, k3A = {0,0,0,0};
    f32x4 hB = {1.0f, 0, 0, 0}, k1B = {0,0,0,0}, k2B = {0,0,0,0}, k3B = {0,0,0,0};
    const float* qpA = quat + (size_t)(rowbase + l15) * TSTEPS * 4;
    const float* qpB = quat + (size_t)(rowbase + 16 + l15) * TSTEPS * 4;

    const bool gm = (g == 1), gl = (g == 3);

#pragma unroll 1
    for (int t = 0; t < TSTEPS; ++t) {
        uint qA01, qA23, qB01, qB23;
        level_pack(*(const f32x4*)(qpA + 4 * t), gm, gl, qA01, qA23);
        level_pack(*(const f32x4*)(qpB + 4 * t), gm, gl, qB01, qB23);
        f32x4 hnA = {0,0,0,0}, hnB = {0,0,0,0};

#pragma unroll
        for (int s = 0; s < 4; ++s) {
            f32x4 hsA = hA, hsB = hB;
            if (s == 1)      { hsA += k1A * (1.0f/3.0f);       hsB += k1B * (1.0f/3.0f); }
            else if (s == 2) { hsA += k2A - k1A * (1.0f/3.0f); hsB += k2B - k1B * (1.0f/3.0f); }
            else if (s == 3) { hsA += k1A - k2A + k3A;         hsB += k1B - k2B + k3B; }

            phase1(hsA, qA01, qA23, gm, gl, w, g, l15, A1a, A1b, sb1, sx1A);
            phase1(hsB, qB01, qB23, gm, gl, w, g, l15, A1a, A1b, sb1, sx1B);
            __syncthreads();

            f32x4 cA0, cA1, cB0, cB1;
            layer2(A2, sb2, sx1A, w, g, l15, cA0, cA1);
            layer2(A2, sb2, sx1B, w, g, l15, cB0, cB1);

            // layer3: fp32 dot; W3 rows read once, shared by both groups
            f32x4 pA = {0,0,0,0}, pB = {0,0,0,0};
#pragma unroll
            for (int mt = 0; mt < 2; ++mt) {
#pragma unroll
                for (int r = 0; r < 4; ++r) {
                    const int j = 32 * w + 16 * mt + 4 * g + r;
                    const f32x4 w3 = *(const f32x4*)&sW3[j * 4];
                    const float xvA = silu_f(mt == 0 ? cA0[r] : cA1[r]);
                    const float xvB = silu_f(mt == 0 ? cB0[r] : cB1[r]);
                    pA += xvA * w3;
                    pB += xvB * w3;
                }
            }
            pA = bfly(pA);
            pB = bfly(pB);
            if (g == 0) {
                *(f32x4*)&sk3[0][w][l15][0] = pA;
                *(f32x4*)&sk3[1][w][l15][0] = pB;
            }
            __syncthreads();

            f32x4 ksA = b3v, ksB = b3v;
#pragma unroll
            for (int w2 = 0; w2 < 4; ++w2) {
                ksA += *(const f32x4*)&sk3[0][w2][l15][0];
                ksB += *(const f32x4*)&sk3[1][w2][l15][0];
            }
            const float wgt = (s == 1 || s == 2) ? 0.375f : 0.125f;
            hnA += ksA * wgt; hnB += ksB * wgt;
            if (s == 0)      { k1A = ksA; k1B = ksB; }
            else if (s == 1) { k2A = ksA; k2B = ksB; }
            else if (s == 2) { k3A = ksA; k3B = ksB; }
        }
        hA += hnA; hB += hnB;
    }

    if (tid < 16)
        *(f32x4*)&out[(size_t)(rowbase + tid) * 4] = hA;
    else if (tid < 32)
        *(f32x4*)&out[(size_t)(rowbase + tid) * 4] = hB;
}

extern "C" void kernel_launch(void* const* d_in, const int* in_sizes, int n_in,
                              void* d_out, int out_size, void* d_ws, size_t ws_size,
                              hipStream_t stream)
{
    const float* quat = (const float*)d_in[0];
    const float* W1   = (const float*)d_in[1];
    const float* b1   = (const float*)d_in[2];
    const float* W2   = (const float*)d_in[3];
    const float* b2   = (const float*)d_in[4];
    const float* W3   = (const float*)d_in[5];
    const float* b3   = (const float*)d_in[6];
    float* out        = (float*)d_out;

    const int B = in_sizes[0] / (TSTEPS * 4);   // 16384
    dim3 grid(B / 32), block(256);
    hipLaunchKernelGGL(odernn_v5, grid, block, 0, stream,
                       quat, W1, b1, W2, b2, W3, b3, out);
}

// Round 6
// 8136.135 us; speedup vs baseline: 1.5019x; 1.1044x over previous
//
#include <hip/hip_runtime.h>

typedef float f32x4 __attribute__((ext_vector_type(4)));
typedef short short8v __attribute__((ext_vector_type(8)));
typedef unsigned int uint;

constexpr int TSTEPS = 512;

union FragU { uint u[4]; short8v v; };

__device__ __forceinline__ float silu_f(float x) {
    return __fdividef(x, 1.0f + __expf(-x));
}

// bf16 round-to-nearest-even; bf16 bit pattern left in TOP 16 bits
__device__ __forceinline__ uint bf16_rne(float x) {
    uint ux = __float_as_uint(x);
    return (ux + 0x7FFFu + ((ux >> 16) & 1u)) & 0xFFFF0000u;
}

// 2-term RNE split: x = h + l + res, |res| <= 2^-16 |x|, UNBIASED
__device__ __forceinline__ void split2u(float x, uint &h, uint &l) {
    h = bf16_rne(x);
    float rem = x - __uint_as_float(h);
    l = bf16_rne(rem);
}

// (a>>16)|(b&0xFFFF0000) in one v_perm_b32
__device__ __forceinline__ uint pack_hi(uint a, uint b) {
    return __builtin_amdgcn_perm(b, a, 0x07060302u);
}

// 4-product dual-split MFMA: computes (Wh+Wl)x(Xh+Xl) exactly (bf16 products
// are exact in fp32); small terms accumulated first.
__device__ __forceinline__ f32x4 mfma4(const short8v *A, short8v Bh, short8v Bl,
                                       f32x4 c) {
    c = __builtin_amdgcn_mfma_f32_16x16x32_bf16(A[1], Bl, c, 0, 0, 0);
    c = __builtin_amdgcn_mfma_f32_16x16x32_bf16(A[1], Bh, c, 0, 0, 0);
    c = __builtin_amdgcn_mfma_f32_16x16x32_bf16(A[0], Bl, c, 0, 0, 0);
    c = __builtin_amdgcn_mfma_f32_16x16x32_bf16(A[0], Bh, c, 0, 0, 0);
    return c;
}

// 256 threads / 4 waves / 16 batch rows per block; grid 1024 -> 3+ blocks/CU.
// layer1: M-split; the 4 k-subgroups carry the 4 level-combos (h,h),(h,l),
//         (l,h),(l,l) of the real K=8 -> ONE MFMA per 16-j tile.
// layer2: M-split, full K=128/wave; x1 crosses waves pre-split (2 bf16 levels).
// layer3: fp32 VALU dot (W3 from LDS) + shfl butterfly + LDS reduce.
__global__ __launch_bounds__(256, 3)
void odernn_v6(const float* __restrict__ quat,
               const float* __restrict__ W1, const float* __restrict__ b1,
               const float* __restrict__ W2, const float* __restrict__ b2,
               const float* __restrict__ W3, const float* __restrict__ b3,
               float* __restrict__ out)
{
    __shared__ short sx1[2 * 16 * 16 * 8];   // 8 KB: [lev][kc][batch][8]
    __shared__ float sb1[128];
    __shared__ float sb2[128];
    __shared__ float sW3[128 * 4];
    __shared__ float sk3[4][16][4];

    const int tid  = threadIdx.x;
    const int w    = tid >> 6;
    const int lane = tid & 63;
    const int l15  = lane & 15;   // batch col (B/C) or M-row j (A)
    const int g    = lane >> 4;   // k-subgroup
    const int rowbase = blockIdx.x * 16;

    if (tid < 128) { sb1[tid] = b1[tid]; sb2[tid] = b2[tid]; }
    for (int i = tid; i < 512; i += 256) sW3[i] = W3[i];

    // W2^T fragments: j = 32w + 16mt + l15, k = 32kt + 8g + e, 2 levels
    short8v A2[2][4][2];
#pragma unroll
    for (int mt = 0; mt < 2; ++mt) {
#pragma unroll
        for (int kt = 0; kt < 4; ++kt) {
#pragma unroll
            for (int e = 0; e < 8; ++e) {
                float x = W2[(32 * kt + 8 * g + e) * 128 + (32 * w + 16 * mt + l15)];
                uint h, l; split2u(x, h, l);
                A2[mt][kt][0][e] = (short)(h >> 16);
                A2[mt][kt][1][e] = (short)(l >> 16);
            }
        }
    }
    // W1^T packed: slot (g,e): A-level = (g<2 ? Wh : Wl)[input e][j]
    short8v A1[2];
#pragma unroll
    for (int mt = 0; mt < 2; ++mt) {
#pragma unroll
        for (int e = 0; e < 8; ++e) {
            float x = W1[e * 128 + (32 * w + 16 * mt + l15)];
            uint h, l; split2u(x, h, l);
            A1[mt][e] = (short)(((g < 2) ? h : l) >> 16);
        }
    }
    f32x4 b3v = *(const f32x4*)b3;

    __syncthreads();

    f32x4 h  = {1.0f, 0, 0, 0};
    f32x4 k1 = {0,0,0,0}, k2 = {0,0,0,0}, k3v = {0,0,0,0};
    const float* qp = quat + (size_t)(rowbase + l15) * TSTEPS * 4;

    const bool gsel = (g & 1);          // B-level select: odd subgroup -> low
    const int  half = (g & 1) * 4;
    const int  kc0  = 4 * w + (g >> 1);

#pragma unroll 1
    for (int t = 0; t < TSTEPS; ++t) {
        f32x4 q = *(const f32x4*)(qp + 4 * t);
        uint qs01, qs23;
        {
            uint qh[4], ql[4];
            split2u(q.x, qh[0], ql[0]); split2u(q.y, qh[1], ql[1]);
            split2u(q.z, qh[2], ql[2]); split2u(q.w, qh[3], ql[3]);
            uint s0 = gsel ? ql[0] : qh[0], s1 = gsel ? ql[1] : qh[1];
            uint s2 = gsel ? ql[2] : qh[2], s3 = gsel ? ql[3] : qh[3];
            qs01 = pack_hi(s0, s1); qs23 = pack_hi(s2, s3);
        }
        f32x4 hnew = {0,0,0,0};

#pragma unroll
        for (int s = 0; s < 4; ++s) {
            f32x4 hs = h;
            if (s == 1)      hs += k1 * (1.0f/3.0f);
            else if (s == 2) hs += k2 - k1 * (1.0f/3.0f);
            else if (s == 3) hs += k1 - k2 + k3v;

            // ---- B0: 2-term split of hs, level by subgroup parity ----
            FragU b0;
            {
                uint hh[4], hl[4];
                split2u(hs.x, hh[0], hl[0]); split2u(hs.y, hh[1], hl[1]);
                split2u(hs.z, hh[2], hl[2]); split2u(hs.w, hh[3], hl[3]);
                uint s0 = gsel ? hl[0] : hh[0], s1 = gsel ? hl[1] : hh[1];
                uint s2 = gsel ? hl[2] : hh[2], s3 = gsel ? hl[3] : hh[3];
                b0.u[0] = pack_hi(s0, s1); b0.u[1] = pack_hi(s2, s3);
                b0.u[2] = qs01;            b0.u[3] = qs23;
            }

            // ---- layer 1: ONE MFMA per 16-j tile ----
            f32x4 c1_0 = *(const f32x4*)&sb1[32 * w + 4 * g];
            f32x4 c1_1 = *(const f32x4*)&sb1[32 * w + 16 + 4 * g];
            c1_0 = __builtin_amdgcn_mfma_f32_16x16x32_bf16(A1[0], b0.v, c1_0, 0, 0, 0);
            c1_1 = __builtin_amdgcn_mfma_f32_16x16x32_bf16(A1[1], b0.v, c1_1, 0, 0, 0);

            // ---- silu + producer-side 2-term split -> LDS ----
#pragma unroll
            for (int mt = 0; mt < 2; ++mt) {
                const f32x4 c1 = mt ? c1_1 : c1_0;
                uint uh[4], ul[4];
#pragma unroll
                for (int r = 0; r < 4; ++r) {
                    float v = silu_f(c1[r]);
                    split2u(v, uh[r], ul[r]);
                }
                const int kc = kc0 + 2 * mt;
                uint2 p0 = {pack_hi(uh[0], uh[1]), pack_hi(uh[2], uh[3])};
                uint2 p1 = {pack_hi(ul[0], ul[1]), pack_hi(ul[2], ul[3])};
                *(uint2*)&sx1[((0 * 16 + kc) * 16 + l15) * 8 + half] = p0;
                *(uint2*)&sx1[((1 * 16 + kc) * 16 + l15) * 8 + half] = p1;
            }
            __syncthreads();

            // ---- layer 2: full-K M-split, two independent chains per tile ----
            f32x4 u0 = *(const f32x4*)&sb2[32 * w + 4 * g],      v0 = {0,0,0,0};
            f32x4 u1 = *(const f32x4*)&sb2[32 * w + 16 + 4 * g], v1 = {0,0,0,0};
#pragma unroll
            for (int kt = 0; kt < 4; ++kt) {
                short8v Bh = *(const short8v*)&sx1[((0 * 16 + kt * 4 + g) * 16 + l15) * 8];
                short8v Bl = *(const short8v*)&sx1[((1 * 16 + kt * 4 + g) * 16 + l15) * 8];
                if (kt & 1) {
                    v0 = mfma4(A2[0][kt], Bh, Bl, v0);
                    v1 = mfma4(A2[1][kt], Bh, Bl, v1);
                } else {
                    u0 = mfma4(A2[0][kt], Bh, Bl, u0);
                    u1 = mfma4(A2[1][kt], Bh, Bl, u1);
                }
            }
            const f32x4 c20 = u0 + v0, c21 = u1 + v1;

            // ---- layer 3: fp32 dot with W3 rows from LDS ----
            f32x4 p = {0,0,0,0};
#pragma unroll
            for (int mt = 0; mt < 2; ++mt) {
#pragma unroll
                for (int r = 0; r < 4; ++r) {
                    const int j = 32 * w + 16 * mt + 4 * g + r;
                    const float xv = silu_f(mt ? c21[r] : c20[r]);
                    p += xv * (*(const f32x4*)&sW3[j * 4]);
                }
            }
#pragma unroll
            for (int mx = 16; mx < 64; mx <<= 1) {
                p.x += __shfl_xor(p.x, mx, 64);
                p.y += __shfl_xor(p.y, mx, 64);
                p.z += __shfl_xor(p.z, mx, 64);
                p.w += __shfl_xor(p.w, mx, 64);
            }
            if (g == 0) *(f32x4*)&sk3[w][l15][0] = p;
            __syncthreads();

            f32x4 ks = b3v;
#pragma unroll
            for (int w2 = 0; w2 < 4; ++w2)
                ks += *(const f32x4*)&sk3[w2][l15][0];

            const float wgt = (s == 1 || s == 2) ? 0.375f : 0.125f;
            hnew += ks * wgt;
            if (s == 0)      k1  = ks;
            else if (s == 1) k2  = ks;
            else if (s == 2) k3v = ks;
        }
        h += hnew;
    }

    if (tid < 16)
        *(f32x4*)&out[(size_t)(rowbase + tid) * 4] = h;
}

extern "C" void kernel_launch(void* const* d_in, const int* in_sizes, int n_in,
                              void* d_out, int out_size, void* d_ws, size_t ws_size,
                              hipStream_t stream)
{
    const float* quat = (const float*)d_in[0];
    const float* W1   = (const float*)d_in[1];
    const float* b1   = (const float*)d_in[2];
    const float* W2   = (const float*)d_in[3];
    const float* b2   = (const float*)d_in[4];
    const float* W3   = (const float*)d_in[5];
    const float* b3   = (const float*)d_in[6];
    float* out        = (float*)d_out;

    const int B = in_sizes[0] / (TSTEPS * 4);   // 16384
    dim3 grid(B / 16), block(256);
    hipLaunchKernelGGL(odernn_v6, grid, block, 0, stream,
                       quat, W1, b1, W2, b2, W3, b3, out);
}

// Round 7
// 7830.499 us; speedup vs baseline: 1.5605x; 1.0390x over previous
//
#include <hip/hip_runtime.h>
#include <hip/hip_bf16.h>

typedef float f32x4 __attribute__((ext_vector_type(4)));
typedef short short8v __attribute__((ext_vector_type(8)));
typedef unsigned int uint;

constexpr int TSTEPS = 512;

union FragU { uint u[4]; short8v v; };

__device__ __forceinline__ float silu_f(float x) {
    return __fdividef(x, 1.0f + __expf(-x));
}

// ---- one-time-setup helpers (launch cost irrelevant, keep simple) ----
__device__ __forceinline__ uint bf16_rne(float x) {
    uint ux = __float_as_uint(x);
    return (ux + 0x7FFFu + ((ux >> 16) & 1u)) & 0xFFFF0000u;
}
__device__ __forceinline__ void split2u(float x, uint &h, uint &l) {
    h = bf16_rne(x);
    float rem = x - __uint_as_float(h);
    l = bf16_rne(rem);
}

// ---- hot-loop split: v_cvt_pk_bf16_f32 based, bit-identical to split2u ----
// packs bf16(a) in low 16, bf16(b) in high 16 (RNE)
__device__ __forceinline__ uint cvtpk(float a, float b) {
    union { __hip_bfloat162 h; uint u; } cv;
    cv.h = __float22bfloat162_rn(make_float2(a, b));
    return cv.u;
}
// split a 4-vector into packed-hi uint2 and packed-lo uint2 (RNE both levels)
__device__ __forceinline__ void split4_pk(const f32x4 v, uint2 &hi, uint2 &lo) {
    hi.x = cvtpk(v.x, v.y);
    hi.y = cvtpk(v.z, v.w);
    float h0 = __uint_as_float(hi.x << 16);
    float h1 = __uint_as_float(hi.x & 0xFFFF0000u);
    float h2 = __uint_as_float(hi.y << 16);
    float h3 = __uint_as_float(hi.y & 0xFFFF0000u);
    lo.x = cvtpk(v.x - h0, v.y - h1);
    lo.y = cvtpk(v.z - h2, v.w - h3);
}

// 4-product dual-split MFMA: computes (Wh+Wl)x(Xh+Xl) exactly; small terms first
__device__ __forceinline__ f32x4 mfma4(const short8v *A, short8v Bh, short8v Bl,
                                       f32x4 c) {
    c = __builtin_amdgcn_mfma_f32_16x16x32_bf16(A[1], Bl, c, 0, 0, 0);
    c = __builtin_amdgcn_mfma_f32_16x16x32_bf16(A[1], Bh, c, 0, 0, 0);
    c = __builtin_amdgcn_mfma_f32_16x16x32_bf16(A[0], Bl, c, 0, 0, 0);
    c = __builtin_amdgcn_mfma_f32_16x16x32_bf16(A[0], Bh, c, 0, 0, 0);
    return c;
}

// 256 threads / 4 waves / 16 batch rows per block.
// layer1: M-split; 4 k-subgroups carry the 4 level-combos of real K=8 -> 1 MFMA/tile.
// layer2: M-split, full K=128/wave; x1 crosses waves pre-split (2 bf16 levels).
// layer3: fp32 VALU dot (W3 from LDS) + shfl butterfly + LDS reduce.
__global__ __launch_bounds__(256, 3)
void odernn_v7(const float* __restrict__ quat,
               const float* __restrict__ W1, const float* __restrict__ b1,
               const float* __restrict__ W2, const float* __restrict__ b2,
               const float* __restrict__ W3, const float* __restrict__ b3,
               float* __restrict__ out)
{
    __shared__ short sx1[2 * 16 * 16 * 8];   // 8 KB: [lev][kc][batch][8]
    __shared__ float sb1[128];
    __shared__ float sb2[128];
    __shared__ float sW3[128 * 4];
    __shared__ float sk3[4][16][4];

    const int tid  = threadIdx.x;
    const int w    = tid >> 6;
    const int lane = tid & 63;
    const int l15  = lane & 15;   // batch col (B/C) or M-row j (A)
    const int g    = lane >> 4;   // k-subgroup
    const int rowbase = blockIdx.x * 16;

    if (tid < 128) { sb1[tid] = b1[tid]; sb2[tid] = b2[tid]; }
    for (int i = tid; i < 512; i += 256) sW3[i] = W3[i];

    // W2^T fragments: j = 32w + 16mt + l15, k = 32kt + 8g + e, 2 levels
    short8v A2[2][4][2];
#pragma unroll
    for (int mt = 0; mt < 2; ++mt) {
#pragma unroll
        for (int kt = 0; kt < 4; ++kt) {
#pragma unroll
            for (int e = 0; e < 8; ++e) {
                float x = W2[(32 * kt + 8 * g + e) * 128 + (32 * w + 16 * mt + l15)];
                uint h, l; split2u(x, h, l);
                A2[mt][kt][0][e] = (short)(h >> 16);
                A2[mt][kt][1][e] = (short)(l >> 16);
            }
        }
    }
    // W1^T packed: slot (g,e): A-level = (g<2 ? Wh : Wl)[input e][j]
    short8v A1[2];
#pragma unroll
    for (int mt = 0; mt < 2; ++mt) {
#pragma unroll
        for (int e = 0; e < 8; ++e) {
            float x = W1[e * 128 + (32 * w + 16 * mt + l15)];
            uint h, l; split2u(x, h, l);
            A1[mt][e] = (short)(((g < 2) ? h : l) >> 16);
        }
    }
    f32x4 b3v = *(const f32x4*)b3;

    __syncthreads();

    f32x4 h  = {1.0f, 0, 0, 0};
    f32x4 k1 = {0,0,0,0}, k2 = {0,0,0,0}, k3v = {0,0,0,0};
    const float* qp = quat + (size_t)(rowbase + l15) * TSTEPS * 4;

    const bool gsel = (g & 1);          // B-level select: odd subgroup -> low
    const int  half = (g & 1) * 4;
    const int  kc0  = 4 * w + (g >> 1);

#pragma unroll 1
    for (int t = 0; t < TSTEPS; ++t) {
        f32x4 q = *(const f32x4*)(qp + 4 * t);
        uint qs01, qs23;
        {
            uint2 qhi, qlo;
            split4_pk(q, qhi, qlo);
            qs01 = gsel ? qlo.x : qhi.x;
            qs23 = gsel ? qlo.y : qhi.y;
        }
        f32x4 hnew = {0,0,0,0};

#pragma unroll
        for (int s = 0; s < 4; ++s) {
            f32x4 hs = h;
            if (s == 1)      hs += k1 * (1.0f/3.0f);
            else if (s == 2) hs += k2 - k1 * (1.0f/3.0f);
            else if (s == 3) hs += k1 - k2 + k3v;

            // ---- B0: 2-term cvt_pk split of hs, level by subgroup parity ----
            FragU b0;
            {
                uint2 hhi, hlo;
                split4_pk(hs, hhi, hlo);
                b0.u[0] = gsel ? hlo.x : hhi.x;
                b0.u[1] = gsel ? hlo.y : hhi.y;
                b0.u[2] = qs01;
                b0.u[3] = qs23;
            }

            // ---- layer 1: ONE MFMA per 16-j tile ----
            f32x4 c1_0 = *(const f32x4*)&sb1[32 * w + 4 * g];
            f32x4 c1_1 = *(const f32x4*)&sb1[32 * w + 16 + 4 * g];
            c1_0 = __builtin_amdgcn_mfma_f32_16x16x32_bf16(A1[0], b0.v, c1_0, 0, 0, 0);
            c1_1 = __builtin_amdgcn_mfma_f32_16x16x32_bf16(A1[1], b0.v, c1_1, 0, 0, 0);

            // ---- silu + producer-side cvt_pk split -> LDS ----
#pragma unroll
            for (int mt = 0; mt < 2; ++mt) {
                const f32x4 c1 = mt ? c1_1 : c1_0;
                f32x4 sv;
#pragma unroll
                for (int r = 0; r < 4; ++r) sv[r] = silu_f(c1[r]);
                uint2 phi, plo;
                split4_pk(sv, phi, plo);
                const int kc = kc0 + 2 * mt;
                *(uint2*)&sx1[((0 * 16 + kc) * 16 + l15) * 8 + half] = phi;
                *(uint2*)&sx1[((1 * 16 + kc) * 16 + l15) * 8 + half] = plo;
            }
            __syncthreads();

            // ---- layer 2: full-K M-split, two independent chains per tile ----
            f32x4 u0 = *(const f32x4*)&sb2[32 * w + 4 * g],      v0 = {0,0,0,0};
            f32x4 u1 = *(const f32x4*)&sb2[32 * w + 16 + 4 * g], v1 = {0,0,0,0};
#pragma unroll
            for (int kt = 0; kt < 4; ++kt) {
                short8v Bh = *(const short8v*)&sx1[((0 * 16 + kt * 4 + g) * 16 + l15) * 8];
                short8v Bl = *(const short8v*)&sx1[((1 * 16 + kt * 4 + g) * 16 + l15) * 8];
                if (kt & 1) {
                    v0 = mfma4(A2[0][kt], Bh, Bl, v0);
                    v1 = mfma4(A2[1][kt], Bh, Bl, v1);
                } else {
                    u0 = mfma4(A2[0][kt], Bh, Bl, u0);
                    u1 = mfma4(A2[1][kt], Bh, Bl, u1);
                }
            }
            const f32x4 c20 = u0 + v0, c21 = u1 + v1;

            // ---- layer 3: fp32 dot with W3 rows from LDS ----
            f32x4 p = {0,0,0,0};
#pragma unroll
            for (int mt = 0; mt < 2; ++mt) {
#pragma unroll
                for (int r = 0; r < 4; ++r) {
                    const int j = 32 * w + 16 * mt + 4 * g + r;
                    const float xv = silu_f(mt ? c21[r] : c20[r]);
                    p += xv * (*(const f32x4*)&sW3[j * 4]);
                }
            }
#pragma unroll
            for (int mx = 16; mx < 64; mx <<= 1) {
                p.x += __shfl_xor(p.x, mx, 64);
                p.y += __shfl_xor(p.y, mx, 64);
                p.z += __shfl_xor(p.z, mx, 64);
                p.w += __shfl_xor(p.w, mx, 64);
            }
            if (g == 0) *(f32x4*)&sk3[w][l15][0] = p;
            __syncthreads();

            f32x4 ks = b3v;
#pragma unroll
            for (int w2 = 0; w2 < 4; ++w2)
                ks += *(const f32x4*)&sk3[w2][l15][0];

            const float wgt = (s == 1 || s == 2) ? 0.375f : 0.125f;
            hnew += ks * wgt;
            if (s == 0)      k1  = ks;
            else if (s == 1) k2  = ks;
            else if (s == 2) k3v = ks;
        }
        h += hnew;
    }

    if (tid < 16)
        *(f32x4*)&out[(size_t)(rowbase + tid) * 4] = h;
}

extern "C" void kernel_launch(void* const* d_in, const int* in_sizes, int n_in,
                              void* d_out, int out_size, void* d_ws, size_t ws_size,
                              hipStream_t stream)
{
    const float* quat = (const float*)d_in[0];
    const float* W1   = (const float*)d_in[1];
    const float* b1   = (const float*)d_in[2];
    const float* W2   = (const float*)d_in[3];
    const float* b2   = (const float*)d_in[4];
    const float* W3   = (const float*)d_in[5];
    const float* b3   = (const float*)d_in[6];
    float* out        = (float*)d_out;

    const int B = in_sizes[0] / (TSTEPS * 4);   // 16384
    dim3 grid(B / 16), block(256);
    hipLaunchKernelGGL(odernn_v7, grid, block, 0, stream,
                       quat, W1, b1, W2, b2, W3, b3, out);
}

// Round 8
// 7384.866 us; speedup vs baseline: 1.6547x; 1.0603x over previous
//
#include <hip/hip_runtime.h>
#include <hip/hip_bf16.h>

typedef float f32x4  __attribute__((ext_vector_type(4)));
typedef float f32x16 __attribute__((ext_vector_type(16)));
typedef short short8v __attribute__((ext_vector_type(8)));
typedef unsigned int uint;

constexpr int TSTEPS = 512;

union FragU { uint u[4]; short8v v; };

__device__ __forceinline__ float silu_f(float x) {
    return __fdividef(x, 1.0f + __expf(-x));
}

// ---- setup-path split (RNE, bit pattern in top 16) ----
__device__ __forceinline__ uint bf16_rne(float x) {
    uint ux = __float_as_uint(x);
    return (ux + 0x7FFFu + ((ux >> 16) & 1u)) & 0xFFFF0000u;
}
__device__ __forceinline__ void split2u(float x, uint &h, uint &l) {
    h = bf16_rne(x);
    float rem = x - __uint_as_float(h);
    l = bf16_rne(rem);
}

// ---- hot-path split via v_cvt_pk_bf16_f32 (bit-identical to split2u) ----
__device__ __forceinline__ uint cvtpk(float a, float b) {
    union { __hip_bfloat162 h; uint u; } cv;
    cv.h = __float22bfloat162_rn(make_float2(a, b));
    return cv.u;
}
__device__ __forceinline__ void split4_pk(const f32x4 v, uint2 &hi, uint2 &lo) {
    hi.x = cvtpk(v.x, v.y);
    hi.y = cvtpk(v.z, v.w);
    float h0 = __uint_as_float(hi.x << 16);
    float h1 = __uint_as_float(hi.x & 0xFFFF0000u);
    float h2 = __uint_as_float(hi.y << 16);
    float h3 = __uint_as_float(hi.y & 0xFFFF0000u);
    lo.x = cvtpk(v.x - h0, v.y - h1);
    lo.y = cvtpk(v.z - h2, v.w - h3);
}

// x1 LDS layout: [lev][kt(8)][gk(2)][b(32)][e(8 shorts)] -> consumer b128 contiguous
#define SX1(lev,kt,gk,b) (((((lev)*8+(kt))*2+(gk))*32+(b))*8)

// 256 threads / 4 waves / 32 batch rows per block; grid 512 = 2 blocks/CU,
// ALL rows resident. 32x32x16 MFMA:
//   C/D: col=lane&31 (batch), row=(reg&3)+8*(reg>>2)+4*(lane>>5) (feature j)
//   A:   row=lane&31 (j),     k=8*(lane>>5)+e
//   B:   col=lane&31 (batch), k=8*(lane>>5)+e
// layer1: K=8 packed into K=16: slots<8 = level-hi A, slots>=8 = level-lo A;
//         two MFMAs with B0a=[own-lev X] and B0b=[swapped-lev X] give all 4
//         split products exactly.
// layer2: M-split (wave w owns j in [32w,32w+32)), full K=128, mfma4 per ktile.
// layer3: fp32 VALU dot (sW3) + 1-step shfl_xor(32) + cross-wave LDS reduce.
__global__ __launch_bounds__(256, 2)
void odernn_v8(const float* __restrict__ quat,
               const float* __restrict__ W1, const float* __restrict__ b1,
               const float* __restrict__ W2, const float* __restrict__ b2,
               const float* __restrict__ W3, const float* __restrict__ b3,
               float* __restrict__ out)
{
    __shared__ short sx1[2 * 8 * 2 * 32 * 8];   // 16 KB
    __shared__ float sb1[128];
    __shared__ float sb2[128];
    __shared__ float sW3[512];
    __shared__ float sk3[4][32][4];             // 2 KB

    const int tid  = threadIdx.x;
    const int w    = tid >> 6;
    const int lane = tid & 63;
    const int b    = lane & 31;    // batch col
    const int gp   = lane >> 5;    // k/lane group (0/1)
    const int rowbase = blockIdx.x * 32;

    if (tid < 128) { sb1[tid] = b1[tid]; sb2[tid] = b2[tid]; }
    for (int i = tid; i < 512; i += 256) sW3[i] = W3[i];

    // ---- persistent weight fragments ----
    // W2^T: A2[kt][lev][e] = lev(W2[k=16kt+8gp+e][j=32w+b])
    short8v A2[8][2];
#pragma unroll
    for (int kt = 0; kt < 8; ++kt) {
#pragma unroll
        for (int e = 0; e < 8; ++e) {
            float x = W2[(16 * kt + 8 * gp + e) * 128 + (32 * w + b)];
            uint h, l; split2u(x, h, l);
            A2[kt][0][e] = (short)(h >> 16);
            A2[kt][1][e] = (short)(l >> 16);
        }
    }
    // W1^T packed: group0 lanes carry Wh, group1 lanes carry Wl (k slots 0-7 / 8-15)
    short8v A1;
#pragma unroll
    for (int e = 0; e < 8; ++e) {
        float x = W1[e * 128 + (32 * w + b)];
        uint h, l; split2u(x, h, l);
        A1[e] = (short)((gp ? l : h) >> 16);
    }
    f32x4 b3v = *(const f32x4*)b3;

    __syncthreads();

    f32x4 h  = {1.0f, 0, 0, 0};
    f32x4 k1 = {0,0,0,0}, k2 = {0,0,0,0}, k3v = {0,0,0,0};
    const float* qp = quat + (size_t)(rowbase + b) * TSTEPS * 4;

#pragma unroll 1
    for (int t = 0; t < TSTEPS; ++t) {
        f32x4 q = *(const f32x4*)(qp + 4 * t);
        uint2 qhi, qlo;
        split4_pk(q, qhi, qlo);
        f32x4 hnew = {0,0,0,0};

#pragma unroll
        for (int s = 0; s < 4; ++s) {
            f32x4 hs = h;
            if (s == 1)      hs += k1 * (1.0f/3.0f);
            else if (s == 2) hs += k2 - k1 * (1.0f/3.0f);
            else if (s == 3) hs += k1 - k2 + k3v;

            // ---- B0 pair: own-level and swapped-level ----
            uint2 hhi, hlo;
            split4_pk(hs, hhi, hlo);
            FragU b0a, b0b;
            b0a.u[0] = gp ? hlo.x : hhi.x;  b0a.u[1] = gp ? hlo.y : hhi.y;
            b0a.u[2] = gp ? qlo.x : qhi.x;  b0a.u[3] = gp ? qlo.y : qhi.y;
            b0b.u[0] = gp ? hhi.x : hlo.x;  b0b.u[1] = gp ? hhi.y : hlo.y;
            b0b.u[2] = gp ? qhi.x : qlo.x;  b0b.u[3] = gp ? qhi.y : qlo.y;

            // ---- layer 1: 2 MFMAs give all 4 level products ----
            f32x16 c1;
#pragma unroll
            for (int qd = 0; qd < 4; ++qd) {
                f32x4 bv = *(const f32x4*)&sb1[32 * w + 8 * qd + 4 * gp];
                c1[4*qd+0] = bv.x; c1[4*qd+1] = bv.y;
                c1[4*qd+2] = bv.z; c1[4*qd+3] = bv.w;
            }
            c1 = __builtin_amdgcn_mfma_f32_32x32x16_bf16(A1, b0a.v, c1, 0, 0, 0);
            c1 = __builtin_amdgcn_mfma_f32_32x32x16_bf16(A1, b0b.v, c1, 0, 0, 0);

            // ---- silu + producer split -> LDS (j = 32w + 8qd + r + 4gp) ----
#pragma unroll
            for (int qd = 0; qd < 4; ++qd) {
                f32x4 sv;
                sv.x = silu_f(c1[4*qd+0]); sv.y = silu_f(c1[4*qd+1]);
                sv.z = silu_f(c1[4*qd+2]); sv.w = silu_f(c1[4*qd+3]);
                uint2 phi, plo;
                split4_pk(sv, phi, plo);
                const int kt = 2 * w + (qd >> 1);
                const int gk = qd & 1;
                *(uint2*)&sx1[SX1(0, kt, gk, b) + 4 * gp] = phi;
                *(uint2*)&sx1[SX1(1, kt, gk, b) + 4 * gp] = plo;
            }
            __syncthreads();

            // ---- layer 2: full K=128, 4-product split MFMA per ktile ----
            f32x16 c2;
#pragma unroll
            for (int qd = 0; qd < 4; ++qd) {
                f32x4 bv = *(const f32x4*)&sb2[32 * w + 8 * qd + 4 * gp];
                c2[4*qd+0] = bv.x; c2[4*qd+1] = bv.y;
                c2[4*qd+2] = bv.z; c2[4*qd+3] = bv.w;
            }
#pragma unroll
            for (int kt = 0; kt < 8; ++kt) {
                short8v Bh = *(const short8v*)&sx1[SX1(0, kt, gp, b)];
                short8v Bl = *(const short8v*)&sx1[SX1(1, kt, gp, b)];
                c2 = __builtin_amdgcn_mfma_f32_32x32x16_bf16(A2[kt][1], Bl, c2, 0, 0, 0);
                c2 = __builtin_amdgcn_mfma_f32_32x32x16_bf16(A2[kt][1], Bh, c2, 0, 0, 0);
                c2 = __builtin_amdgcn_mfma_f32_32x32x16_bf16(A2[kt][0], Bl, c2, 0, 0, 0);
                c2 = __builtin_amdgcn_mfma_f32_32x32x16_bf16(A2[kt][0], Bh, c2, 0, 0, 0);
            }

            // ---- layer 3: fp32 dot over the lane's 16 j values ----
            f32x4 p = {0,0,0,0};
#pragma unroll
            for (int i = 0; i < 16; ++i) {
                const int j = 32 * w + 8 * (i >> 2) + (i & 3) + 4 * gp;
                const float xv = silu_f(c2[i]);
                p += xv * (*(const f32x4*)&sW3[j * 4]);
            }
            p.x += __shfl_xor(p.x, 32, 64);
            p.y += __shfl_xor(p.y, 32, 64);
            p.z += __shfl_xor(p.z, 32, 64);
            p.w += __shfl_xor(p.w, 32, 64);
            if (lane < 32) *(f32x4*)&sk3[w][lane][0] = p;
            __syncthreads();

            f32x4 ks = b3v;
#pragma unroll
            for (int w2 = 0; w2 < 4; ++w2)
                ks += *(const f32x4*)&sk3[w2][b][0];

            const float wgt = (s == 1 || s == 2) ? 0.375f : 0.125f;
            hnew += ks * wgt;
            if (s == 0)      k1  = ks;
            else if (s == 1) k2  = ks;
            else if (s == 2) k3v = ks;
        }
        h += hnew;
    }

    if (tid < 32)
        *(f32x4*)&out[(size_t)(rowbase + tid) * 4] = h;
}

extern "C" void kernel_launch(void* const* d_in, const int* in_sizes, int n_in,
                              void* d_out, int out_size, void* d_ws, size_t ws_size,
                              hipStream_t stream)
{
    const float* quat = (const float*)d_in[0];
    const float* W1   = (const float*)d_in[1];
    const float* b1   = (const float*)d_in[2];
    const float* W2   = (const float*)d_in[3];
    const float* b2   = (const float*)d_in[4];
    const float* W3   = (const float*)d_in[5];
    const float* b3   = (const float*)d_in[6];
    float* out        = (float*)d_out;

    const int B = in_sizes[0] / (TSTEPS * 4);   // 16384
    dim3 grid(B / 32), block(256);
    hipLaunchKernelGGL(odernn_v8, grid, block, 0, stream,
                       quat, W1, b1, W2, b2, W3, b3, out);
}